// Round 5
// baseline (57.697 us; speedup 1.0000x reference)
//
#include <hip/hip_runtime.h>
#include <math.h>

#define K_CENTERS 512
#define T_TAB 4096
#define XMIN_T (-6.0f)
#define XMAX_T (6.0f)
#define H_TAB ((XMAX_T - XMIN_T) / (float)T_TAB)
#define INV_H ((float)T_TAB / (XMAX_T - XMIN_T))
#define SORT_BLOCKS 8
#define TAB_NODE_BLOCKS 129                     /* 129*32 = 4128 >= 4097 nodes */
#define NPROD (SORT_BLOCKS + TAB_NODE_BLOCKS)   /* 137 producer blocks */
#define MAGIC 0x5F3C2A1B

// Single dispatch, producer->consumer flag sync (no cg::grid().sync()).
// Phase 1:
//   blocks 0..7    : rank-sort 512 centers -> pair[rank]={value,(float)origIdx}
//   blocks 8..136  : 32 table nodes each, 8 lanes/node. For node n at
//                    x_n = XMIN + n*h: softmax-mean F at x_n and x_{n+1},
//                    counts c0=#{c<x_n}, c1=#{c<x_{n+1}}.
//                    tab4[n] = {F0, F1-F0, bits(jlo=c0-3), bits(jhi=c1+2)}
//   each producer: __threadfence() + release-store flags[b]=MAGIC
// All blocks spin on the 137 flags (relaxed agent loads + s_sleep), then:
// Phase 2 (all 512 blocks, 4 elems/thread):
//   one float4 tab read -> softout interp + candidate range; exact f32-faithful
//   argmin scan over sorted neighbors in LDS (reference d=x-c, d2=d*d rounding,
//   first-min tie-break on original index).
// Outputs (concat): zbar(=hardout), softout, hardout, symbols(as float).
__global__ __launch_bounds__(256) void fused_k(const float* __restrict__ data,
                                               const float* __restrict__ centers,
                                               int* __restrict__ flags,
                                               float2* __restrict__ pair,
                                               float4* __restrict__ tab4,
                                               float* __restrict__ out, int N) {
    __shared__ alignas(16) float2 lsP[K_CENTERS];
    int t = threadIdx.x;
    int b = blockIdx.x;

    int base = (b * 256 + t) * 4;
    float4 xv = make_float4(0.f, 0.f, 0.f, 0.f);
    if (base < N) xv = *reinterpret_cast<const float4*>(data + base);  // prefetch under phase 1

    // ---------------- phase 1 (producers) ----------------
    if (b < SORT_BLOCKS) {
        float* c = (float*)lsP;                // reuse LDS as float[512]
        c[t] = centers[t];
        c[t + 256] = centers[t + 256];
        __syncthreads();
        int cidx = b * 64 + (t >> 2);          // 4 threads per center
        int p = t & 3;
        float x = c[cidx];
        const float4* c4 = reinterpret_cast<const float4*>(c);
        int q0 = p * 32;
        int rank = 0;
#pragma unroll 8
        for (int i = 0; i < 32; ++i) {
            float4 cj = c4[q0 + i];
            int j = (q0 + i) * 4;
            rank += (cj.x < x || (cj.x == x && (j + 0) < cidx)) ? 1 : 0;
            rank += (cj.y < x || (cj.y == x && (j + 1) < cidx)) ? 1 : 0;
            rank += (cj.z < x || (cj.z == x && (j + 2) < cidx)) ? 1 : 0;
            rank += (cj.w < x || (cj.w == x && (j + 3) < cidx)) ? 1 : 0;
        }
        rank += __shfl_xor(rank, 1);
        rank += __shfl_xor(rank, 2);
        if (p == 0) pair[rank] = make_float2(x, (float)cidx);
        __syncthreads();
        if (t == 0) {
            __threadfence();
            __hip_atomic_store(&flags[b], MAGIC, __ATOMIC_RELEASE, __HIP_MEMORY_SCOPE_AGENT);
        }
    } else if (b < NPROD) {
        int n = (b - SORT_BLOCKS) * 32 + (t >> 3);   // 8 lanes per node
        int s = t & 7;
        if (n <= T_TAB) {
            float xn  = XMIN_T + (float)n * H_TAB;
            float xn1 = xn + H_TAB;
            float w0 = 0.f, wc0 = 0.f, w1 = 0.f, wc1 = 0.f;
            int c0 = 0, c1 = 0;
            int k0 = s * 64;
#pragma unroll 4
            for (int q = 0; q < 64; ++q) {
                float cv = centers[k0 + q];
                float d0 = xn - cv;
                float e0 = __expf(-d0 * d0);         // SIGMA = 1
                w0 += e0; wc0 = fmaf(e0, cv, wc0); c0 += (cv < xn) ? 1 : 0;
                float d1 = xn1 - cv;
                float e1 = __expf(-d1 * d1);
                w1 += e1; wc1 = fmaf(e1, cv, wc1); c1 += (cv < xn1) ? 1 : 0;
            }
#pragma unroll
            for (int m = 1; m < 8; m <<= 1) {
                w0 += __shfl_xor(w0, m);  wc0 += __shfl_xor(wc0, m);
                w1 += __shfl_xor(w1, m);  wc1 += __shfl_xor(wc1, m);
                c0 += __shfl_xor(c0, m);  c1  += __shfl_xor(c1, m);
            }
            if (s == 0) {
                float F0 = wc0 / w0;
                float F1 = wc1 / w1;
                int jlo = max(c0 - 3, 0);
                int jhi = min(c1 + 2, K_CENTERS - 1);
                tab4[n] = make_float4(F0, F1 - F0, __int_as_float(jlo), __int_as_float(jhi));
            }
        }
        __syncthreads();
        if (t == 0) {
            __threadfence();
            __hip_atomic_store(&flags[b], MAGIC, __ATOMIC_RELEASE, __HIP_MEMORY_SCOPE_AGENT);
        }
    }

    // ---------------- sync: wait for all 137 producers ----------------
    if (t < NPROD) {
        while (__hip_atomic_load(&flags[t], __ATOMIC_RELAXED, __HIP_MEMORY_SCOPE_AGENT) != MAGIC)
            __builtin_amdgcn_s_sleep(2);
    }
    __syncthreads();
    __threadfence();   // acquire: invalidate stale cache lines before reading pair/tab4

    // ---------------- phase 2 ----------------
    lsP[t] = pair[t];
    lsP[t + 256] = pair[t + 256];
    __syncthreads();

    if (base >= N) return;

    float xs[4] = {xv.x, xv.y, xv.z, xv.w};
    float zb[4], so[4], sy[4];

#pragma unroll
    for (int e = 0; e < 4; ++e) {
        float x = xs[e];
        float u = fmaf(x, INV_H, -XMIN_T * INV_H);   // (x - XMIN)/h
        int i0 = (int)u;                              // trunc; negatives clamp below
        i0 = min(max(i0, 0), T_TAB - 1);
        float frac = u - (float)i0;
        frac = fminf(fmaxf(frac, 0.f), 1.f);
        float4 tv = tab4[i0];                         // {F, slope, jlo, jhi} one 16B load
        so[e] = fmaf(frac, tv.y, tv.x);
        int jlo = __float_as_int(tv.z);
        int jhi = __float_as_int(tv.w);
        float bd2 = 3.4e38f;
        float bfo = 1.0e9f;       // original index as float (exact for <512)
        float bc = 0.f;
        for (int j = jlo; j <= jhi; ++j) {
            float2 P = lsP[j];
            float d = x - P.x;        // same rounding as reference
            float d2 = d * d;         // same rounding as reference
            bool better = (d2 < bd2) || ((d2 == bd2) && (P.y < bfo));
            if (better) { bd2 = d2; bfo = P.y; bc = P.x; }
        }
        zb[e] = bc;                   // zbar forward value == hardout
        sy[e] = bfo;
    }

    *reinterpret_cast<float4*>(out + base)         = make_float4(zb[0], zb[1], zb[2], zb[3]);
    *reinterpret_cast<float4*>(out + N + base)     = make_float4(so[0], so[1], so[2], so[3]);
    *reinterpret_cast<float4*>(out + 2 * N + base) = make_float4(zb[0], zb[1], zb[2], zb[3]);
    *reinterpret_cast<float4*>(out + 3 * N + base) = make_float4(sy[0], sy[1], sy[2], sy[3]);
}

extern "C" void kernel_launch(void* const* d_in, const int* in_sizes, int n_in,
                              void* d_out, int out_size, void* d_ws, size_t ws_size,
                              hipStream_t stream) {
    const float* data    = (const float*)d_in[0];
    const float* centers = (const float*)d_in[1];
    float* out = (float*)d_out;
    int N = in_sizes[0];   // 524288

    // ws layout (byte offsets): flags @0 (137 ints), pair @4096 (512 float2),
    // tab4 @8192 (4097 float4). 4KB gap keeps flag-line traffic away from data.
    int*    flags = (int*)d_ws;
    float2* pair  = (float2*)((char*)d_ws + 4096);
    float4* tab4  = (float4*)((char*)d_ws + 8192);

    int blocks = (N / 4 + 255) / 256;   // 512
    fused_k<<<blocks, 256, 0, stream>>>(data, centers, flags, pair, tab4, out, N);
}

// Round 6
// 19.887 us; speedup vs baseline: 2.9013x; 2.9013x over previous
//
#include <hip/hip_runtime.h>
#include <math.h>

#define K_CENTERS 512
#define T_TAB 4096
#define XMIN_T (-6.0f)
#define XMAX_T (6.0f)
#define H_TAB ((XMAX_T - XMIN_T) / (float)T_TAB)
#define INV_H ((float)T_TAB / (XMAX_T - XMIN_T))
#define SORT_BLOCKS 8
#define TAB_NODE_BLOCKS 129                     /* 129*32 = 4128 >= 4097 nodes */
#define NPROD (SORT_BLOCKS + TAB_NODE_BLOCKS)   /* 137 producer blocks */
#define NCOMM (K_CENTERS + T_TAB + 1)           /* 4609 float2 slots */
#define MAGIC 0x5F3C2A1Bu

__device__ __forceinline__ unsigned long long f2u(float2 v) {
    union { float2 f; unsigned long long u; } c; c.f = v; return c.u;
}

// Single dispatch. All cross-block communication uses RELAXED agent-scope
// atomics only — no release/acquire, no __threadfence, so the compiler emits
// zero buffer_wbl2 / buffer_inv (R5's 55us was exactly those per-block L2
// flush/invalidate ops). Protocol: producer atomic-stores data, __syncthreads
// (drains every wave's vmcnt before s_barrier), then atomic-stores its flag;
// consumers poll flags (uncached) and read data ONLY via uncached atomic
// loads -> no stale-L1/L2 hazard, fence-free.
// Phase 1: blocks 0..7 rank-sort centers -> comm[rank]={val,(float)origIdx};
//          blocks 8..136: 32 table nodes each (8 lanes/node):
//          comm[512+n] = {softmax-mean(x_n), (float)#{c < x_n}}.
// All blocks: spin on 137 flags, stage comm -> LDS (19 u64 atomic loads/thr),
// Phase 2: per element (4/thread): table interp softout; exact f32-faithful
// argmin scan of sorted neighbors (reference d=x-c, d2=d*d rounding, first-min
// tie-break on original index).
// Outputs (concat): zbar(=hardout), softout, hardout, symbols(as float).
__global__ __launch_bounds__(256) void fused_k(const float* __restrict__ data,
                                               const float* __restrict__ centers,
                                               unsigned int* __restrict__ flags,
                                               unsigned long long* __restrict__ comm,
                                               float* __restrict__ out, int N) {
    __shared__ alignas(16) float2 buf[NCOMM + 3];   // 4612 float2 = 36896 B
    int t = threadIdx.x;
    int b = blockIdx.x;

    int base = (b * 256 + t) * 4;
    float4 xv = make_float4(0.f, 0.f, 0.f, 0.f);
    if (base < N) xv = *reinterpret_cast<const float4*>(data + base);  // prefetch under phase 1

    // ---------------- phase 1 (producers) ----------------
    if (b < SORT_BLOCKS) {
        float* c = (float*)buf;                // reuse LDS (overwritten at staging)
        c[t] = centers[t];
        c[t + 256] = centers[t + 256];
        __syncthreads();
        int cidx = b * 64 + (t >> 2);          // 4 threads per center
        int p = t & 3;
        float x = c[cidx];
        const float4* c4 = reinterpret_cast<const float4*>(c);
        int q0 = p * 32;
        int rank = 0;
#pragma unroll 8
        for (int i = 0; i < 32; ++i) {
            float4 cj = c4[q0 + i];
            int j = (q0 + i) * 4;
            rank += (cj.x < x || (cj.x == x && (j + 0) < cidx)) ? 1 : 0;
            rank += (cj.y < x || (cj.y == x && (j + 1) < cidx)) ? 1 : 0;
            rank += (cj.z < x || (cj.z == x && (j + 2) < cidx)) ? 1 : 0;
            rank += (cj.w < x || (cj.w == x && (j + 3) < cidx)) ? 1 : 0;
        }
        rank += __shfl_xor(rank, 1);
        rank += __shfl_xor(rank, 2);
        if (p == 0)
            __hip_atomic_store(&comm[rank], f2u(make_float2(x, (float)cidx)),
                               __ATOMIC_RELAXED, __HIP_MEMORY_SCOPE_AGENT);
        __syncthreads();   // drains all waves' vmcnt before barrier
        if (t == 0)
            __hip_atomic_store(&flags[b], MAGIC, __ATOMIC_RELAXED, __HIP_MEMORY_SCOPE_AGENT);
    } else if (b < NPROD) {
        int n = (b - SORT_BLOCKS) * 32 + (t >> 3);   // 8 lanes per node
        int s = t & 7;
        if (n <= T_TAB) {
            float xn = XMIN_T + (float)n * H_TAB;
            float w = 0.f, wc = 0.f;
            int ic = 0;
            int k0 = s * 64;
#pragma unroll 8
            for (int q = 0; q < 64; ++q) {
                float cv = centers[k0 + q];
                float d = xn - cv;
                float e = __expf(-d * d);            // SIGMA = 1
                w += e;
                wc = fmaf(e, cv, wc);
                ic += (cv < xn) ? 1 : 0;
            }
            w += __shfl_xor(w, 1); wc += __shfl_xor(wc, 1); ic += __shfl_xor(ic, 1);
            w += __shfl_xor(w, 2); wc += __shfl_xor(wc, 2); ic += __shfl_xor(ic, 2);
            w += __shfl_xor(w, 4); wc += __shfl_xor(wc, 4); ic += __shfl_xor(ic, 4);
            if (s == 0)
                __hip_atomic_store(&comm[K_CENTERS + n], f2u(make_float2(wc / w, (float)ic)),
                                   __ATOMIC_RELAXED, __HIP_MEMORY_SCOPE_AGENT);
        }
        __syncthreads();
        if (t == 0)
            __hip_atomic_store(&flags[b], MAGIC, __ATOMIC_RELAXED, __HIP_MEMORY_SCOPE_AGENT);
    }

    // ---------------- sync: wait for all 137 producers (relaxed polls) ----------------
    if (t < NPROD) {
        while (__hip_atomic_load(&flags[t], __ATOMIC_RELAXED, __HIP_MEMORY_SCOPE_AGENT) != MAGIC)
            __builtin_amdgcn_s_sleep(1);
    }
    __syncthreads();

    // ---------------- stage comm -> LDS via uncached atomic loads ----------------
    {
        unsigned long long* dstu = reinterpret_cast<unsigned long long*>(buf);
        for (int i = t; i < NCOMM; i += 256)
            dstu[i] = __hip_atomic_load(&comm[i], __ATOMIC_RELAXED, __HIP_MEMORY_SCOPE_AGENT);
    }
    __syncthreads();
    const float2* lsP  = buf;                // sorted {value, origIdx}
    const float2* tabL = buf + K_CENTERS;    // {F[n], cnt[n]}

    // ---------------- phase 2 ----------------
    if (base >= N) return;

    float xs[4] = {xv.x, xv.y, xv.z, xv.w};
    float zb[4], so[4], sy[4];

#pragma unroll
    for (int e = 0; e < 4; ++e) {
        float x = xs[e];
        float u = (x - XMIN_T) * INV_H;
        int i0 = (int)floorf(u);
        i0 = min(max(i0, 0), T_TAB - 1);
        float frac = u - (float)i0;
        frac = fminf(fmaxf(frac, 0.f), 1.f);
        float2 r0 = tabL[i0];
        float2 r1 = tabL[i0 + 1];
        so[e] = fmaf(frac, r1.x - r0.x, r0.x);
        int jlo = max((int)r0.y - 3, 0);
        int jhi = min((int)r1.y + 2, K_CENTERS - 1);
        float bd2 = 3.4e38f;
        float bfo = 1.0e9f;      // original index as float (exact for <512)
        float bc = 0.f;
        for (int j = jlo; j <= jhi; ++j) {
            float2 P = lsP[j];
            float d = x - P.x;       // same rounding as reference
            float d2 = d * d;        // same rounding as reference
            bool better = (d2 < bd2) || ((d2 == bd2) && (P.y < bfo));
            if (better) { bd2 = d2; bfo = P.y; bc = P.x; }
        }
        zb[e] = bc;                  // zbar forward value == hardout
        sy[e] = bfo;
    }

    *reinterpret_cast<float4*>(out + base)         = make_float4(zb[0], zb[1], zb[2], zb[3]);
    *reinterpret_cast<float4*>(out + N + base)     = make_float4(so[0], so[1], so[2], so[3]);
    *reinterpret_cast<float4*>(out + 2 * N + base) = make_float4(zb[0], zb[1], zb[2], zb[3]);
    *reinterpret_cast<float4*>(out + 3 * N + base) = make_float4(sy[0], sy[1], sy[2], sy[3]);
}

extern "C" void kernel_launch(void* const* d_in, const int* in_sizes, int n_in,
                              void* d_out, int out_size, void* d_ws, size_t ws_size,
                              hipStream_t stream) {
    const float* data    = (const float*)d_in[0];
    const float* centers = (const float*)d_in[1];
    float* out = (float*)d_out;
    int N = in_sizes[0];   // 524288

    // ws layout: flags @0 (137 uints) | comm @4096 (4609 u64: 512 pairs + 4097 table)
    unsigned int*       flags = (unsigned int*)d_ws;
    unsigned long long* comm  = (unsigned long long*)((char*)d_ws + 4096);

    int blocks = (N / 4 + 255) / 256;   // 512
    fused_k<<<blocks, 256, 0, stream>>>(data, centers, flags, comm, out, N);
}